// Round 4
// baseline (1705.728 us; speedup 1.0000x reference)
//
#include <hip/hip_runtime.h>
#include <hip/hip_fp16.h>

typedef _Float16 f16;
typedef _Float16 f16x2 __attribute__((ext_vector_type(2)));
typedef _Float16 f16x8 __attribute__((ext_vector_type(8)));
typedef float    f32x4 __attribute__((ext_vector_type(4)));
typedef unsigned int u32;
typedef unsigned long long u64;

#define BN_EPS 1e-5f

static constexpr int BB  = 32;    // batch
static constexpr int CC  = 128;   // channels
static constexpr int HWN = 1024;  // H*W = L
static constexpr int RIN = 256;
static constexpr int RH  = 512;
static constexpr int OCN = 128;

// ---------------------------------------------------------------- BN stats
__global__ void bn_stats_kernel(const float* __restrict__ x,
                                const float* __restrict__ gamma,
                                const float* __restrict__ beta,
                                float* __restrict__ scale,
                                float* __restrict__ shift) {
    int c = blockIdx.x;
    int tid = threadIdx.x;
    float s = 0.f, s2 = 0.f;
    const float* xc = x + (size_t)c * HWN;
    for (int idx = tid; idx < BB * HWN; idx += 256) {
        int b = idx >> 10, hw = idx & 1023;
        float v = xc[(size_t)b * (CC * HWN) + hw];
        s += v; s2 += v * v;
    }
    for (int off = 32; off > 0; off >>= 1) {
        s  += __shfl_down(s, off, 64);
        s2 += __shfl_down(s2, off, 64);
    }
    __shared__ float ls[4], ls2[4];
    int wv = tid >> 6, ln = tid & 63;
    if (ln == 0) { ls[wv] = s; ls2[wv] = s2; }
    __syncthreads();
    if (tid == 0) {
        float ts  = ls[0] + ls[1] + ls[2] + ls[3];
        float ts2 = ls2[0] + ls2[1] + ls2[2] + ls2[3];
        const float inv_n = 1.0f / (BB * HWN);
        float mean = ts * inv_n;
        float var  = ts2 * inv_n - mean * mean;
        float rstd = rsqrtf(var + BN_EPS);
        float sc = gamma[c] * rstd;
        scale[c] = sc;
        shift[c] = beta[c] - mean * sc;
    }
}

// ------------------------------------------- normalize + transpose -> A1 f16
__global__ void prep_x_kernel(const float* __restrict__ x,
                              const float* __restrict__ scale,
                              const float* __restrict__ shift,
                              f16* __restrict__ A1) {
    __shared__ float tile[32][33];
    int tx = threadIdx.x, ty = threadIdx.y;  // 32 x 8
    int hb = blockIdx.x, cb = blockIdx.y, b = blockIdx.z;
    #pragma unroll
    for (int k = 0; k < 4; k++) {
        int c  = cb * 32 + ty + 8 * k;
        int hw = hb * 32 + tx;
        tile[ty + 8 * k][tx] = x[(size_t)b * (CC * HWN) + (size_t)c * HWN + hw];
    }
    __syncthreads();
    #pragma unroll
    for (int k = 0; k < 4; k++) {
        int hw = hb * 32 + ty + 8 * k;
        int c  = cb * 32 + tx;
        float v = tile[tx][ty + 8 * k];
        A1[(size_t)(b * HWN + hw) * CC + c] = (f16)(v * scale[c] + shift[c]);
    }
}

// ------------------------------------------------------------ weight prep
__global__ void prep_w_kernel(const float* __restrict__ w_in,
                              const float* __restrict__ w_ih,
                              const float* __restrict__ w_out,
                              const float* __restrict__ w_hh,
                              const float* __restrict__ b_ih,
                              const float* __restrict__ b_hh,
                              f16* __restrict__ w_in_h,
                              f16* __restrict__ w_ih_h,
                              f16* __restrict__ w_out_h,
                              u32* __restrict__ wr,
                              float* __restrict__ bihh,
                              u64* __restrict__ comm) {
    int idx = blockIdx.x * 256 + threadIdx.x;
    if (idx < 32768) { w_in_h[idx] = (f16)w_in[idx]; return; }
    idx -= 32768;
    if (idx < 131072) { w_ih_h[idx] = (f16)w_ih[idx]; return; }
    idx -= 131072;
    if (idx < 65536) { w_out_h[idx] = (f16)w_out[idx]; return; }
    idx -= 65536;
    if (idx < 131072) {
        // word idx -> (slice s, thread t, reg k); reg k = r*16+n
        int s = idx >> 15, rem = idx & 32767;
        int t = rem >> 6, k = rem & 63;
        int r = k >> 4, n = k & 15;
        int jg = t & 31, sl = t >> 5;
        int j  = s * 128 + 4 * jg + r;       // output row
        int i2 = sl * 16 + n;                // h-pair index
        f16 lo = (f16)w_hh[(size_t)j * 512 + 2 * i2];
        f16 hi = (f16)w_hh[(size_t)j * 512 + 2 * i2 + 1];
        wr[idx] = (u32)__builtin_bit_cast(unsigned short, lo) |
                  ((u32)__builtin_bit_cast(unsigned short, hi) << 16);
        return;
    }
    idx -= 131072;
    if (idx < 512) { bihh[idx] = b_ih[idx] + b_hh[idx]; return; }
    idx -= 512;
    if (idx < 16384) comm[idx] = 0ULL;
}

// ------------------------------------------------------------- MFMA GEMM
template <int MODE>
__global__ void gemm_kernel(const f16* __restrict__ A,
                            const f16* __restrict__ W,
                            const float* __restrict__ bias,
                            void* __restrict__ outp,
                            int N, int K) {
    int wave = threadIdx.x >> 6;
    int lane = threadIdx.x & 63;
    int q = lane >> 4, r = lane & 15;
    int bm = blockIdx.x * 256 + wave * 64;
    int bn = blockIdx.y * 64;

    f32x4 acc[4][4];
    #pragma unroll
    for (int i = 0; i < 4; i++)
        #pragma unroll
        for (int j = 0; j < 4; j++)
            acc[i][j] = (f32x4){0.f, 0.f, 0.f, 0.f};

    const f16* Ap = A + (size_t)(bm + r) * K + 8 * q;
    const f16* Wp = W + (size_t)(bn + r) * K + 8 * q;

    for (int k = 0; k < K; k += 32) {
        f16x8 av[4], bv[4];
        #pragma unroll
        for (int i = 0; i < 4; i++)
            av[i] = *(const f16x8*)(Ap + (size_t)(16 * i) * K + k);
        #pragma unroll
        for (int i = 0; i < 4; i++)
            bv[i] = *(const f16x8*)(Wp + (size_t)(16 * i) * K + k);
        #pragma unroll
        for (int mi = 0; mi < 4; mi++)
            #pragma unroll
            for (int ni = 0; ni < 4; ni++)
                acc[mi][ni] = __builtin_amdgcn_mfma_f32_16x16x32_f16(
                    av[mi], bv[ni], acc[mi][ni], 0, 0, 0);
    }

    #pragma unroll
    for (int mi = 0; mi < 4; mi++) {
        #pragma unroll
        for (int ni = 0; ni < 4; ni++) {
            int col = bn + 16 * ni + r;
            float bval = bias[col];
            #pragma unroll
            for (int i = 0; i < 4; i++) {
                int row = bm + 16 * mi + 4 * q + i;
                float val = acc[mi][ni][i] + bval;
                if (MODE == 0) {
                    val = val - tanhf(val);
                    ((f16*)outp)[(size_t)row * N + col] = (f16)val;
                } else if (MODE == 1) {
                    ((f16*)outp)[(size_t)row * N + col] = (f16)val;
                } else {
                    int b = row >> 10, hw = row & 1023;
                    ((float*)outp)[(size_t)b * (OCN * HWN) + (size_t)col * HWN + hw] = val;
                }
            }
        }
    }
}

// ---------------------------------------------------------------- RNN scan
// 4 slices x 32 batches = 128 WGs; W_hh slice register-resident (64 VGPRs/
// thread — __launch_bounds__(512,2) raises the VGPR cap to 256 so the
// allocator does NOT spill w[] to scratch; round-3's VGPR_Count=52 proved it
// had). Cross-WG h exchange: RELAXED u64 atomics (payload+tag in one word,
// parity double-buffer). Gather runs on waves 4-6 (t in [256,448)) so
// pollers are not serialized behind finalize/tanh; 2-deep pipelined poll
// keeps two loads in flight.
__device__ __forceinline__ float dot2acc(u32 w, f16x2 h, float c) {
#if __has_builtin(__builtin_amdgcn_fdot2)
    return __builtin_amdgcn_fdot2(__builtin_bit_cast(f16x2, w), h, c, false);
#else
    f16x2 a = __builtin_bit_cast(f16x2, w);
    return c + (float)a[0] * (float)h[0] + (float)a[1] * (float)h[1];
#endif
}

__global__ __launch_bounds__(512, 2) void rnn_kernel(const u32* __restrict__ WR,
                                                     f16* __restrict__ xh,
                                                     u64* __restrict__ comm) {
    const int wg = blockIdx.x;
    const int b  = wg & 31;   // batch  (4 slices of a batch share wg%8 -> same XCD)
    const int s  = wg >> 5;   // slice: rows [128s, 128s+128)
    const int t  = threadIdx.x;
    const int jg = t & 31;    // 4 rows: 128s + 4jg .. +3
    const int sl = t >> 5;    // 16 h-pair slices of 16 pairs

    __shared__ __align__(16) f16 hbuf[512];
    __shared__ float part[16][128];

    // load this thread's 64 weight words into registers (one-time)
    u32 w[64];
    {
        const uint4* wp = (const uint4*)(WR + ((size_t)(s * 512 + t) << 6));
        #pragma unroll
        for (int i = 0; i < 16; i++) {
            uint4 v = wp[i];
            w[4*i+0] = v.x; w[4*i+1] = v.y; w[4*i+2] = v.z; w[4*i+3] = v.w;
        }
    }
    if (t < 256) ((u32*)hbuf)[t] = 0u;
    __syncthreads();

    f16* xb = xh + (size_t)b * (HWN * RH) + s * 128;  // + step*RH + t
    float xnext = 0.f;
    if (t < 128) xnext = (float)xb[t];

    u64* cb = comm + (size_t)b * 256;  // [parity]*8192 + b*256 + slice*64 + word

    for (int step = 0; step < HWN; step++) {
        float xcur = xnext;
        if (t < 128 && step + 1 < HWN)
            xnext = (float)xb[(size_t)(step + 1) * RH + t];

        // ---- compute partial y for 4 rows over this thread's 16 h-pairs
        const uint4* hq = (const uint4*)hbuf;
        uint4 q0 = hq[sl*4+0], q1 = hq[sl*4+1], q2 = hq[sl*4+2], q3 = hq[sl*4+3];
        u32 hv[16] = {q0.x,q0.y,q0.z,q0.w, q1.x,q1.y,q1.z,q1.w,
                      q2.x,q2.y,q2.z,q2.w, q3.x,q3.y,q3.z,q3.w};
        float a0 = 0.f, a1 = 0.f, a2 = 0.f, a3 = 0.f;
        #pragma unroll
        for (int n = 0; n < 16; n++) {
            f16x2 hh = __builtin_bit_cast(f16x2, hv[n]);
            a0 = dot2acc(w[n],      hh, a0);
            a1 = dot2acc(w[16 + n], hh, a1);
            a2 = dot2acc(w[32 + n], hh, a2);
            a3 = dot2acc(w[48 + n], hh, a3);
        }
        *(f32x4*)&part[sl][4 * jg] = (f32x4){a0, a1, a2, a3};
        __syncthreads();

        const u32 tag = (u32)(step + 1);
        const size_t pbase = (size_t)(tag & 1) * 8192;

        // ---- waves 4-6: poll for the 3 partner slices (start immediately)
        if (t >= 256 && t < 448) {
            int pi = (t - 256) >> 6;
            int widx = t & 63;
            int p = pi + (pi >= s ? 1 : 0);
            u64* addr = &cb[pbase + p * 64 + widx];
            u64 v  = __hip_atomic_load(addr, __ATOMIC_RELAXED, __HIP_MEMORY_SCOPE_AGENT);
            u64 v2 = __hip_atomic_load(addr, __ATOMIC_RELAXED, __HIP_MEMORY_SCOPE_AGENT);
            int guard = 0;
            while ((u32)(v >> 32) != tag && ++guard < (1 << 17)) {
                v = v2;
                v2 = __hip_atomic_load(addr, __ATOMIC_RELAXED, __HIP_MEMORY_SCOPE_AGENT);
            }
            ((u32*)hbuf)[p * 64 + widx] = (u32)v;
        }
        // ---- waves 0-1: finalize own 128 rows, publish ASAP
        if (t < 128) {
            float y = xcur;
            #pragma unroll
            for (int k = 0; k < 16; k++) y += part[k][t];
            float h = tanhf(y);
            f16 hf = (f16)h;
            u32 hu = (u32)__builtin_bit_cast(unsigned short, hf);
            u32 other = (u32)__shfl_down((int)hu, 1, 64);
            if ((t & 1) == 0) {
                u64 v = ((u64)tag << 32) | (u64)(hu | (other << 16));
                __hip_atomic_store(&cb[pbase + s * 64 + (t >> 1)], v,
                                   __ATOMIC_RELAXED, __HIP_MEMORY_SCOPE_AGENT);
            }
            hbuf[s * 128 + t] = hf;                 // own slice into local h
            xb[(size_t)step * RH + t] = hf;         // hs output (in place)
        }
        __syncthreads();
    }
}

// ------------------------------------------------------------------ launch
extern "C" void kernel_launch(void* const* d_in, const int* in_sizes, int n_in,
                              void* d_out, int out_size, void* d_ws, size_t ws_size,
                              hipStream_t stream) {
    const float* x     = (const float*)d_in[0];
    const float* gamma = (const float*)d_in[1];
    const float* beta  = (const float*)d_in[2];
    const float* w_in  = (const float*)d_in[3];
    const float* b_in  = (const float*)d_in[4];
    const float* w_ih  = (const float*)d_in[5];
    const float* b_ih  = (const float*)d_in[6];
    const float* w_hh  = (const float*)d_in[7];
    const float* b_hh  = (const float*)d_in[8];
    const float* w_out = (const float*)d_in[9];
    const float* b_out = (const float*)d_in[10];

    char* ws = (char*)d_ws;
    float* scale   = (float*)(ws + 0);         //   512 B
    float* shift   = (float*)(ws + 512);       //   512 B
    float* bihh    = (float*)(ws + 1024);      //  2 KB
    f16*   w_in_h  = (f16*)(ws + 4096);        // 64 KB
    f16*   w_ih_h  = (f16*)(ws + 69632);       // 256 KB
    f16*   w_out_h = (f16*)(ws + 331776);      // 128 KB
    u32*   wr      = (u32*)(ws + 462848);      // 512 KB packed W_hh
    u64*   comm    = (u64*)(ws + 987136);      // 128 KB h-exchange
    f16*   xh      = (f16*)(ws + 1179648);     // 32 MB xgate, overwritten by hs
    f16*   A1      = (f16*)(ws + 34734080);    //  8 MB
    f16*   inp     = (f16*)(ws + 43122688);    // 16 MB (ends 59899904)

    bn_stats_kernel<<<128, 256, 0, stream>>>(x, gamma, beta, scale, shift);
    prep_w_kernel<<<1474, 256, 0, stream>>>(w_in, w_ih, w_out, w_hh, b_ih, b_hh,
                                            w_in_h, w_ih_h, w_out_h, wr, bihh, comm);
    prep_x_kernel<<<dim3(32, 4, 32), dim3(32, 8), 0, stream>>>(x, scale, shift, A1);
    gemm_kernel<0><<<dim3(128, 4), 256, 0, stream>>>(A1, w_in_h, b_in, (void*)inp, RIN, CC);
    gemm_kernel<1><<<dim3(128, 8), 256, 0, stream>>>(inp, w_ih_h, bihh, (void*)xh, RH, RIN);
    rnn_kernel<<<128, 512, 0, stream>>>(wr, xh, comm);
    gemm_kernel<2><<<dim3(128, 2), 256, 0, stream>>>(xh, w_out_h, b_out, d_out, OCN, RH);
}

// Round 5
// 1601.999 us; speedup vs baseline: 1.0647x; 1.0647x over previous
//
#include <hip/hip_runtime.h>
#include <hip/hip_fp16.h>

typedef _Float16 f16;
typedef _Float16 f16x2 __attribute__((ext_vector_type(2)));
typedef _Float16 f16x8 __attribute__((ext_vector_type(8)));
typedef float    f32x4 __attribute__((ext_vector_type(4)));
typedef unsigned int u32;
typedef unsigned long long u64;

#define BN_EPS 1e-5f

static constexpr int BB  = 32;    // batch
static constexpr int CC  = 128;   // channels
static constexpr int HWN = 1024;  // H*W = L
static constexpr int RIN = 256;
static constexpr int RH  = 512;
static constexpr int OCN = 128;

// ---------------------------------------------------------------- BN stats
__global__ void bn_stats_kernel(const float* __restrict__ x,
                                const float* __restrict__ gamma,
                                const float* __restrict__ beta,
                                float* __restrict__ scale,
                                float* __restrict__ shift) {
    int c = blockIdx.x;
    int tid = threadIdx.x;
    float s = 0.f, s2 = 0.f;
    const float* xc = x + (size_t)c * HWN;
    for (int idx = tid; idx < BB * HWN; idx += 256) {
        int b = idx >> 10, hw = idx & 1023;
        float v = xc[(size_t)b * (CC * HWN) + hw];
        s += v; s2 += v * v;
    }
    for (int off = 32; off > 0; off >>= 1) {
        s  += __shfl_down(s, off, 64);
        s2 += __shfl_down(s2, off, 64);
    }
    __shared__ float ls[4], ls2[4];
    int wv = tid >> 6, ln = tid & 63;
    if (ln == 0) { ls[wv] = s; ls2[wv] = s2; }
    __syncthreads();
    if (tid == 0) {
        float ts  = ls[0] + ls[1] + ls[2] + ls[3];
        float ts2 = ls2[0] + ls2[1] + ls2[2] + ls2[3];
        const float inv_n = 1.0f / (BB * HWN);
        float mean = ts * inv_n;
        float var  = ts2 * inv_n - mean * mean;
        float rstd = rsqrtf(var + BN_EPS);
        float sc = gamma[c] * rstd;
        scale[c] = sc;
        shift[c] = beta[c] - mean * sc;
    }
}

// ------------------------------------------- normalize + transpose -> A1 f16
__global__ void prep_x_kernel(const float* __restrict__ x,
                              const float* __restrict__ scale,
                              const float* __restrict__ shift,
                              f16* __restrict__ A1) {
    __shared__ float tile[32][33];
    int tx = threadIdx.x, ty = threadIdx.y;  // 32 x 8
    int hb = blockIdx.x, cb = blockIdx.y, b = blockIdx.z;
    #pragma unroll
    for (int k = 0; k < 4; k++) {
        int c  = cb * 32 + ty + 8 * k;
        int hw = hb * 32 + tx;
        tile[ty + 8 * k][tx] = x[(size_t)b * (CC * HWN) + (size_t)c * HWN + hw];
    }
    __syncthreads();
    #pragma unroll
    for (int k = 0; k < 4; k++) {
        int hw = hb * 32 + ty + 8 * k;
        int c  = cb * 32 + tx;
        float v = tile[tx][ty + 8 * k];
        A1[(size_t)(b * HWN + hw) * CC + c] = (f16)(v * scale[c] + shift[c]);
    }
}

// ------------------------------------------------------------ weight prep
__global__ void prep_w_kernel(const float* __restrict__ w_in,
                              const float* __restrict__ w_ih,
                              const float* __restrict__ w_out,
                              const float* __restrict__ w_hh,
                              const float* __restrict__ b_ih,
                              const float* __restrict__ b_hh,
                              f16* __restrict__ w_in_h,
                              f16* __restrict__ w_ih_h,
                              f16* __restrict__ w_out_h,
                              u32* __restrict__ wr,
                              float* __restrict__ bihh,
                              u64* __restrict__ comm) {
    int idx = blockIdx.x * 256 + threadIdx.x;
    if (idx < 32768) { w_in_h[idx] = (f16)w_in[idx]; return; }
    idx -= 32768;
    if (idx < 131072) { w_ih_h[idx] = (f16)w_ih[idx]; return; }
    idx -= 131072;
    if (idx < 65536) { w_out_h[idx] = (f16)w_out[idx]; return; }
    idx -= 65536;
    if (idx < 131072) {
        // word idx -> (slice s, thread t, reg k); reg k = r*16+n
        int s = idx >> 15, rem = idx & 32767;
        int t = rem >> 6, k = rem & 63;
        int r = k >> 4, n = k & 15;
        int jg = t & 31, sl = t >> 5;
        int j  = s * 128 + 4 * jg + r;       // output row
        int i2 = sl * 16 + n;                // h-pair index
        f16 lo = (f16)w_hh[(size_t)j * 512 + 2 * i2];
        f16 hi = (f16)w_hh[(size_t)j * 512 + 2 * i2 + 1];
        wr[idx] = (u32)__builtin_bit_cast(unsigned short, lo) |
                  ((u32)__builtin_bit_cast(unsigned short, hi) << 16);
        return;
    }
    idx -= 131072;
    if (idx < 512) { bihh[idx] = b_ih[idx] + b_hh[idx]; return; }
    idx -= 512;
    if (idx < 16384) comm[idx] = 0ULL;
}

// ------------------------------------------------------------- MFMA GEMM
template <int MODE>
__global__ void gemm_kernel(const f16* __restrict__ A,
                            const f16* __restrict__ W,
                            const float* __restrict__ bias,
                            void* __restrict__ outp,
                            int N, int K) {
    int wave = threadIdx.x >> 6;
    int lane = threadIdx.x & 63;
    int q = lane >> 4, r = lane & 15;
    int bm = blockIdx.x * 256 + wave * 64;
    int bn = blockIdx.y * 64;

    f32x4 acc[4][4];
    #pragma unroll
    for (int i = 0; i < 4; i++)
        #pragma unroll
        for (int j = 0; j < 4; j++)
            acc[i][j] = (f32x4){0.f, 0.f, 0.f, 0.f};

    const f16* Ap = A + (size_t)(bm + r) * K + 8 * q;
    const f16* Wp = W + (size_t)(bn + r) * K + 8 * q;

    for (int k = 0; k < K; k += 32) {
        f16x8 av[4], bv[4];
        #pragma unroll
        for (int i = 0; i < 4; i++)
            av[i] = *(const f16x8*)(Ap + (size_t)(16 * i) * K + k);
        #pragma unroll
        for (int i = 0; i < 4; i++)
            bv[i] = *(const f16x8*)(Wp + (size_t)(16 * i) * K + k);
        #pragma unroll
        for (int mi = 0; mi < 4; mi++)
            #pragma unroll
            for (int ni = 0; ni < 4; ni++)
                acc[mi][ni] = __builtin_amdgcn_mfma_f32_16x16x32_f16(
                    av[mi], bv[ni], acc[mi][ni], 0, 0, 0);
    }

    #pragma unroll
    for (int mi = 0; mi < 4; mi++) {
        #pragma unroll
        for (int ni = 0; ni < 4; ni++) {
            int col = bn + 16 * ni + r;
            float bval = bias[col];
            #pragma unroll
            for (int i = 0; i < 4; i++) {
                int row = bm + 16 * mi + 4 * q + i;
                float val = acc[mi][ni][i] + bval;
                if (MODE == 0) {
                    val = val - tanhf(val);
                    ((f16*)outp)[(size_t)row * N + col] = (f16)val;
                } else if (MODE == 1) {
                    ((f16*)outp)[(size_t)row * N + col] = (f16)val;
                } else {
                    int b = row >> 10, hw = row & 1023;
                    ((float*)outp)[(size_t)b * (OCN * HWN) + (size_t)col * HWN + hw] = val;
                }
            }
        }
    }
}

// ---------------------------------------------------------------- RNN scan
// 4 slices x 32 batches = 128 WGs. W_hh slice held in 16 named uint4 SSA
// values (NO local array: rounds 3/4 proved `u32 w[64]` fails SROA — loops
// aren't unrolled before SROA runs, the array lands in scratch, and every
// step re-streams 128 KB/WG from L2; VGPR_Count=52 was the tell). Named
// scalars are guaranteed register-resident. Cross-WG h exchange: RELAXED
// u64 atomics (payload+tag in one word, parity double-buffer); pollers on
// waves 4-6, finalize on waves 0-1.
__device__ __forceinline__ float dot2acc(u32 w, f16x2 h, float c) {
#if __has_builtin(__builtin_amdgcn_fdot2)
    return __builtin_amdgcn_fdot2(__builtin_bit_cast(f16x2, w), h, c, false);
#else
    f16x2 a = __builtin_bit_cast(f16x2, w);
    return c + (float)a[0] * (float)h[0] + (float)a[1] * (float)h[1];
#endif
}

#define ROW16(acc, WA, WB, WC, WD)                                  \
    acc = dot2acc(WA.x, H0,  acc); acc = dot2acc(WA.y, H1,  acc);   \
    acc = dot2acc(WA.z, H2,  acc); acc = dot2acc(WA.w, H3,  acc);   \
    acc = dot2acc(WB.x, H4,  acc); acc = dot2acc(WB.y, H5,  acc);   \
    acc = dot2acc(WB.z, H6,  acc); acc = dot2acc(WB.w, H7,  acc);   \
    acc = dot2acc(WC.x, H8,  acc); acc = dot2acc(WC.y, H9,  acc);   \
    acc = dot2acc(WC.z, H10, acc); acc = dot2acc(WC.w, H11, acc);   \
    acc = dot2acc(WD.x, H12, acc); acc = dot2acc(WD.y, H13, acc);   \
    acc = dot2acc(WD.z, H14, acc); acc = dot2acc(WD.w, H15, acc)

__global__ __launch_bounds__(512, 2) void rnn_kernel(const u32* __restrict__ WR,
                                                     f16* __restrict__ xh,
                                                     u64* __restrict__ comm) {
    const int wg = blockIdx.x;
    const int b  = wg & 31;   // batch  (4 slices of a batch share wg%8 -> same XCD)
    const int s  = wg >> 5;   // slice: rows [128s, 128s+128)
    const int t  = threadIdx.x;
    const int jg = t & 31;    // 4 rows: 128s + 4jg .. +3
    const int sl = t >> 5;    // 16 h-pair slices of 16 pairs

    __shared__ __align__(16) f16 hbuf[512];
    __shared__ float part[16][128];

    // this thread's 64 weight words -> 16 named uint4 SSA values (registers)
    const uint4* wp = (const uint4*)(WR + ((size_t)(s * 512 + t) << 6));
    uint4 W0 = wp[0],  W1 = wp[1],  W2 = wp[2],  W3 = wp[3];
    uint4 W4 = wp[4],  W5 = wp[5],  W6 = wp[6],  W7 = wp[7];
    uint4 W8 = wp[8],  W9 = wp[9],  W10 = wp[10], W11 = wp[11];
    uint4 W12 = wp[12], W13 = wp[13], W14 = wp[14], W15 = wp[15];

    if (t < 256) ((u32*)hbuf)[t] = 0u;
    __syncthreads();

    f16* xb = xh + (size_t)b * (HWN * RH) + s * 128;  // + step*RH + t
    float xnext = 0.f;
    if (t < 128) xnext = (float)xb[t];

    u64* cb = comm + (size_t)b * 256;  // [parity]*8192 + b*256 + slice*64 + word
    const uint4* hq = (const uint4*)hbuf;

    for (int step = 0; step < HWN; step++) {
        float xcur = xnext;
        if (t < 128 && step + 1 < HWN)
            xnext = (float)xb[(size_t)(step + 1) * RH + t];

        // ---- partial y for 4 rows over this thread's 16 h-pairs
        uint4 q0 = hq[sl*4+0], q1 = hq[sl*4+1], q2 = hq[sl*4+2], q3 = hq[sl*4+3];
        f16x2 H0  = __builtin_bit_cast(f16x2, q0.x), H1  = __builtin_bit_cast(f16x2, q0.y);
        f16x2 H2  = __builtin_bit_cast(f16x2, q0.z), H3  = __builtin_bit_cast(f16x2, q0.w);
        f16x2 H4  = __builtin_bit_cast(f16x2, q1.x), H5  = __builtin_bit_cast(f16x2, q1.y);
        f16x2 H6  = __builtin_bit_cast(f16x2, q1.z), H7  = __builtin_bit_cast(f16x2, q1.w);
        f16x2 H8  = __builtin_bit_cast(f16x2, q2.x), H9  = __builtin_bit_cast(f16x2, q2.y);
        f16x2 H10 = __builtin_bit_cast(f16x2, q2.z), H11 = __builtin_bit_cast(f16x2, q2.w);
        f16x2 H12 = __builtin_bit_cast(f16x2, q3.x), H13 = __builtin_bit_cast(f16x2, q3.y);
        f16x2 H14 = __builtin_bit_cast(f16x2, q3.z), H15 = __builtin_bit_cast(f16x2, q3.w);
        float a0 = 0.f, a1 = 0.f, a2 = 0.f, a3 = 0.f;
        ROW16(a0, W0,  W1,  W2,  W3);
        ROW16(a1, W4,  W5,  W6,  W7);
        ROW16(a2, W8,  W9,  W10, W11);
        ROW16(a3, W12, W13, W14, W15);
        *(f32x4*)&part[sl][4 * jg] = (f32x4){a0, a1, a2, a3};
        __syncthreads();

        const u32 tag = (u32)(step + 1);
        const size_t pbase = (size_t)(tag & 1) * 8192;

        // ---- waves 4-6: poll for the 3 partner slices (start immediately)
        if (t >= 256 && t < 448) {
            int pi = (t - 256) >> 6;
            int widx = t & 63;
            int p = pi + (pi >= s ? 1 : 0);
            u64* addr = &cb[pbase + p * 64 + widx];
            u64 v  = __hip_atomic_load(addr, __ATOMIC_RELAXED, __HIP_MEMORY_SCOPE_AGENT);
            u64 v2 = __hip_atomic_load(addr, __ATOMIC_RELAXED, __HIP_MEMORY_SCOPE_AGENT);
            int guard = 0;
            while ((u32)(v >> 32) != tag && ++guard < (1 << 17)) {
                v = v2;
                v2 = __hip_atomic_load(addr, __ATOMIC_RELAXED, __HIP_MEMORY_SCOPE_AGENT);
            }
            ((u32*)hbuf)[p * 64 + widx] = (u32)v;
        }
        // ---- waves 0-1: finalize own 128 rows, publish ASAP
        if (t < 128) {
            float y = xcur;
            #pragma unroll
            for (int k = 0; k < 16; k++) y += part[k][t];
            float h = tanhf(y);
            f16 hf = (f16)h;
            u32 hu = (u32)__builtin_bit_cast(unsigned short, hf);
            u32 other = (u32)__shfl_down((int)hu, 1, 64);
            if ((t & 1) == 0) {
                u64 v = ((u64)tag << 32) | (u64)(hu | (other << 16));
                __hip_atomic_store(&cb[pbase + s * 64 + (t >> 1)], v,
                                   __ATOMIC_RELAXED, __HIP_MEMORY_SCOPE_AGENT);
            }
            hbuf[s * 128 + t] = hf;                 // own slice into local h
            xb[(size_t)step * RH + t] = hf;         // hs output (in place)
        }
        __syncthreads();
    }
}

// ------------------------------------------------------------------ launch
extern "C" void kernel_launch(void* const* d_in, const int* in_sizes, int n_in,
                              void* d_out, int out_size, void* d_ws, size_t ws_size,
                              hipStream_t stream) {
    const float* x     = (const float*)d_in[0];
    const float* gamma = (const float*)d_in[1];
    const float* beta  = (const float*)d_in[2];
    const float* w_in  = (const float*)d_in[3];
    const float* b_in  = (const float*)d_in[4];
    const float* w_ih  = (const float*)d_in[5];
    const float* b_ih  = (const float*)d_in[6];
    const float* w_hh  = (const float*)d_in[7];
    const float* b_hh  = (const float*)d_in[8];
    const float* w_out = (const float*)d_in[9];
    const float* b_out = (const float*)d_in[10];

    char* ws = (char*)d_ws;
    float* scale   = (float*)(ws + 0);         //   512 B
    float* shift   = (float*)(ws + 512);       //   512 B
    float* bihh    = (float*)(ws + 1024);      //  2 KB
    f16*   w_in_h  = (f16*)(ws + 4096);        // 64 KB
    f16*   w_ih_h  = (f16*)(ws + 69632);       // 256 KB
    f16*   w_out_h = (f16*)(ws + 331776);      // 128 KB
    u32*   wr      = (u32*)(ws + 462848);      // 512 KB packed W_hh
    u64*   comm    = (u64*)(ws + 987136);      // 128 KB h-exchange
    f16*   xh      = (f16*)(ws + 1179648);     // 32 MB xgate, overwritten by hs
    f16*   A1      = (f16*)(ws + 34734080);    //  8 MB
    f16*   inp     = (f16*)(ws + 43122688);    // 16 MB (ends 59899904)

    bn_stats_kernel<<<128, 256, 0, stream>>>(x, gamma, beta, scale, shift);
    prep_w_kernel<<<1474, 256, 0, stream>>>(w_in, w_ih, w_out, w_hh, b_ih, b_hh,
                                            w_in_h, w_ih_h, w_out_h, wr, bihh, comm);
    prep_x_kernel<<<dim3(32, 4, 32), dim3(32, 8), 0, stream>>>(x, scale, shift, A1);
    gemm_kernel<0><<<dim3(128, 4), 256, 0, stream>>>(A1, w_in_h, b_in, (void*)inp, RIN, CC);
    gemm_kernel<1><<<dim3(128, 8), 256, 0, stream>>>(inp, w_ih_h, bihh, (void*)xh, RH, RIN);
    rnn_kernel<<<128, 512, 0, stream>>>(wr, xh, comm);
    gemm_kernel<2><<<dim3(128, 2), 256, 0, stream>>>(xh, w_out_h, b_out, d_out, OCN, RH);
}

// Round 7
// 1598.302 us; speedup vs baseline: 1.0672x; 1.0023x over previous
//
#include <hip/hip_runtime.h>
#include <hip/hip_fp16.h>

typedef _Float16 f16;
typedef _Float16 f16x2 __attribute__((ext_vector_type(2)));
typedef _Float16 f16x8 __attribute__((ext_vector_type(8)));
typedef float    f32x4 __attribute__((ext_vector_type(4)));
typedef unsigned int u32;
typedef unsigned long long u64;

#define BN_EPS 1e-5f

static constexpr int BB  = 32;    // batch
static constexpr int CC  = 128;   // channels
static constexpr int HWN = 1024;  // H*W = L
static constexpr int RIN = 256;
static constexpr int RH  = 512;
static constexpr int OCN = 128;

// ---------------------------------------------------------------- BN stats
__global__ void bn_stats_kernel(const float* __restrict__ x,
                                const float* __restrict__ gamma,
                                const float* __restrict__ beta,
                                float* __restrict__ scale,
                                float* __restrict__ shift) {
    int c = blockIdx.x;
    int tid = threadIdx.x;
    float s = 0.f, s2 = 0.f;
    const float* xc = x + (size_t)c * HWN;
    for (int idx = tid; idx < BB * HWN; idx += 256) {
        int b = idx >> 10, hw = idx & 1023;
        float v = xc[(size_t)b * (CC * HWN) + hw];
        s += v; s2 += v * v;
    }
    for (int off = 32; off > 0; off >>= 1) {
        s  += __shfl_down(s, off, 64);
        s2 += __shfl_down(s2, off, 64);
    }
    __shared__ float ls[4], ls2[4];
    int wv = tid >> 6, ln = tid & 63;
    if (ln == 0) { ls[wv] = s; ls2[wv] = s2; }
    __syncthreads();
    if (tid == 0) {
        float ts  = ls[0] + ls[1] + ls[2] + ls[3];
        float ts2 = ls2[0] + ls2[1] + ls2[2] + ls2[3];
        const float inv_n = 1.0f / (BB * HWN);
        float mean = ts * inv_n;
        float var  = ts2 * inv_n - mean * mean;
        float rstd = rsqrtf(var + BN_EPS);
        float sc = gamma[c] * rstd;
        scale[c] = sc;
        shift[c] = beta[c] - mean * sc;
    }
}

// ------------------------------------------- normalize + transpose -> A1 f16
__global__ void prep_x_kernel(const float* __restrict__ x,
                              const float* __restrict__ scale,
                              const float* __restrict__ shift,
                              f16* __restrict__ A1) {
    __shared__ float tile[32][33];
    int tx = threadIdx.x, ty = threadIdx.y;  // 32 x 8
    int hb = blockIdx.x, cb = blockIdx.y, b = blockIdx.z;
    #pragma unroll
    for (int k = 0; k < 4; k++) {
        int c  = cb * 32 + ty + 8 * k;
        int hw = hb * 32 + tx;
        tile[ty + 8 * k][tx] = x[(size_t)b * (CC * HWN) + (size_t)c * HWN + hw];
    }
    __syncthreads();
    #pragma unroll
    for (int k = 0; k < 4; k++) {
        int hw = hb * 32 + ty + 8 * k;
        int c  = cb * 32 + tx;
        float v = tile[tx][ty + 8 * k];
        A1[(size_t)(b * HWN + hw) * CC + c] = (f16)(v * scale[c] + shift[c]);
    }
}

// ------------------------------------------------------------ weight prep
__global__ void prep_w_kernel(const float* __restrict__ w_in,
                              const float* __restrict__ w_ih,
                              const float* __restrict__ w_out,
                              const float* __restrict__ w_hh,
                              const float* __restrict__ b_ih,
                              const float* __restrict__ b_hh,
                              f16* __restrict__ w_in_h,
                              f16* __restrict__ w_ih_h,
                              f16* __restrict__ w_out_h,
                              u32* __restrict__ wr,
                              float* __restrict__ bihh,
                              u64* __restrict__ comm) {
    int idx = blockIdx.x * 256 + threadIdx.x;
    if (idx < 32768) { w_in_h[idx] = (f16)w_in[idx]; return; }
    idx -= 32768;
    if (idx < 131072) { w_ih_h[idx] = (f16)w_ih[idx]; return; }
    idx -= 131072;
    if (idx < 65536) { w_out_h[idx] = (f16)w_out[idx]; return; }
    idx -= 65536;
    if (idx < 131072) {
        // word idx -> (slice s, thread t, reg k); reg k = r*16+n
        int s = idx >> 15, rem = idx & 32767;
        int t = rem >> 6, k = rem & 63;
        int r = k >> 4, n = k & 15;
        int jg = t & 31, sl = t >> 5;
        int j  = s * 128 + 4 * jg + r;       // output row
        int i2 = sl * 16 + n;                // h-pair index
        f16 lo = (f16)w_hh[(size_t)j * 512 + 2 * i2];
        f16 hi = (f16)w_hh[(size_t)j * 512 + 2 * i2 + 1];
        wr[idx] = (u32)__builtin_bit_cast(unsigned short, lo) |
                  ((u32)__builtin_bit_cast(unsigned short, hi) << 16);
        return;
    }
    idx -= 131072;
    if (idx < 512) { bihh[idx] = b_ih[idx] + b_hh[idx]; return; }
    idx -= 512;
    if (idx < 16384) comm[idx] = 0ULL;
}

// ------------------------------------------------------------- MFMA GEMM
template <int MODE>
__global__ void gemm_kernel(const f16* __restrict__ A,
                            const f16* __restrict__ W,
                            const float* __restrict__ bias,
                            void* __restrict__ outp,
                            int N, int K) {
    int wave = threadIdx.x >> 6;
    int lane = threadIdx.x & 63;
    int q = lane >> 4, r = lane & 15;
    int bm = blockIdx.x * 256 + wave * 64;
    int bn = blockIdx.y * 64;

    f32x4 acc[4][4];
    #pragma unroll
    for (int i = 0; i < 4; i++)
        #pragma unroll
        for (int j = 0; j < 4; j++)
            acc[i][j] = (f32x4){0.f, 0.f, 0.f, 0.f};

    const f16* Ap = A + (size_t)(bm + r) * K + 8 * q;
    const f16* Wp = W + (size_t)(bn + r) * K + 8 * q;

    for (int k = 0; k < K; k += 32) {
        f16x8 av[4], bv[4];
        #pragma unroll
        for (int i = 0; i < 4; i++)
            av[i] = *(const f16x8*)(Ap + (size_t)(16 * i) * K + k);
        #pragma unroll
        for (int i = 0; i < 4; i++)
            bv[i] = *(const f16x8*)(Wp + (size_t)(16 * i) * K + k);
        #pragma unroll
        for (int mi = 0; mi < 4; mi++)
            #pragma unroll
            for (int ni = 0; ni < 4; ni++)
                acc[mi][ni] = __builtin_amdgcn_mfma_f32_16x16x32_f16(
                    av[mi], bv[ni], acc[mi][ni], 0, 0, 0);
    }

    #pragma unroll
    for (int mi = 0; mi < 4; mi++) {
        #pragma unroll
        for (int ni = 0; ni < 4; ni++) {
            int col = bn + 16 * ni + r;
            float bval = bias[col];
            #pragma unroll
            for (int i = 0; i < 4; i++) {
                int row = bm + 16 * mi + 4 * q + i;
                float val = acc[mi][ni][i] + bval;
                if (MODE == 0) {
                    val = val - tanhf(val);
                    ((f16*)outp)[(size_t)row * N + col] = (f16)val;
                } else if (MODE == 1) {
                    ((f16*)outp)[(size_t)row * N + col] = (f16)val;
                } else {
                    int b = row >> 10, hw = row & 1023;
                    ((float*)outp)[(size_t)b * (OCN * HWN) + (size_t)col * HWN + hw] = val;
                }
            }
        }
    }
}

// ---------------------------------------------------------------- RNN scan
// 4 slices x 32 batches = 128 WGs (1 per CU). W_hh slice kept in registers.
// Mechanism (rounds 3-6 history): local array -> SROA fails -> scratch;
// named SSA from a __restrict__ pointer -> invariant-load REMAT re-streams
// the weights from L2 every step (VGPR_Count stuck at 52); raw asm loads
// without early-clobber -> address clobber crash. This round: provenance of
// the weight pointer is hidden behind an empty asm volatile and WR/comm are
// NOT restrict -> the in-loop atomic store may alias the weight memory ->
// remat inside the loop is illegal -> the 16 uint4 values MUST stay live in
// VGPRs (budget 256 via launch_bounds(512,2), live ~120, no spill).
// Cross-WG h exchange: RELAXED u64 atomics (payload+tag in one word,
// parity double-buffer); pollers on waves 4-6, finalize on waves 0-1.
__device__ __forceinline__ float dot2acc(u32 w, f16x2 h, float c) {
#if __has_builtin(__builtin_amdgcn_fdot2)
    return __builtin_amdgcn_fdot2(__builtin_bit_cast(f16x2, w), h, c, false);
#else
    f16x2 a = __builtin_bit_cast(f16x2, w);
    return c + (float)a[0] * (float)h[0] + (float)a[1] * (float)h[1];
#endif
}

#define ROW16(acc, WA, WB, WC, WD)                                  \
    acc = dot2acc(WA.x, H0,  acc); acc = dot2acc(WA.y, H1,  acc);   \
    acc = dot2acc(WA.z, H2,  acc); acc = dot2acc(WA.w, H3,  acc);   \
    acc = dot2acc(WB.x, H4,  acc); acc = dot2acc(WB.y, H5,  acc);   \
    acc = dot2acc(WB.z, H6,  acc); acc = dot2acc(WB.w, H7,  acc);   \
    acc = dot2acc(WC.x, H8,  acc); acc = dot2acc(WC.y, H9,  acc);   \
    acc = dot2acc(WC.z, H10, acc); acc = dot2acc(WC.w, H11, acc);   \
    acc = dot2acc(WD.x, H12, acc); acc = dot2acc(WD.y, H13, acc);   \
    acc = dot2acc(WD.z, H14, acc); acc = dot2acc(WD.w, H15, acc)

__global__ __launch_bounds__(512, 2) void rnn_kernel(const u32* WR,
                                                     f16* __restrict__ xh,
                                                     u64* comm) {
    const int wg = blockIdx.x;
    const int b  = wg & 31;   // batch  (4 slices of a batch share wg%8 -> same XCD)
    const int s  = wg >> 5;   // slice: rows [128s, 128s+128)
    const int t  = threadIdx.x;
    const int jg = t & 31;    // 4 rows: 128s + 4jg .. +3
    const int sl = t >> 5;    // 16 h-pair slices of 16 pairs

    __shared__ __align__(16) f16 hbuf[512];
    __shared__ float part[16][128];

    // this thread's 64 weight words -> 16 named uint4 values. Pointer
    // provenance hidden so the loads can't be proven invariant (comm store
    // in the loop may alias) -> values pinned in registers, not remat'ed.
    unsigned long long wpa =
        (unsigned long long)(WR + ((size_t)(s * 512 + t) << 6));
    asm volatile("" : "+v"(wpa));
    const uint4* wp = (const uint4*)wpa;
    uint4 W0 = wp[0],  W1 = wp[1],  W2 = wp[2],  W3 = wp[3];
    uint4 W4 = wp[4],  W5 = wp[5],  W6 = wp[6],  W7 = wp[7];
    uint4 W8 = wp[8],  W9 = wp[9],  W10 = wp[10], W11 = wp[11];
    uint4 W12 = wp[12], W13 = wp[13], W14 = wp[14], W15 = wp[15];

    if (t < 256) ((u32*)hbuf)[t] = 0u;
    __syncthreads();

    f16* xb = xh + (size_t)b * (HWN * RH) + s * 128;  // + step*RH + t
    float xnext = 0.f;
    if (t < 128) xnext = (float)xb[t];

    u64* cb = comm + (size_t)b * 256;  // [parity]*8192 + b*256 + slice*64 + word
    const uint4* hq = (const uint4*)hbuf;

    for (int step = 0; step < HWN; step++) {
        float xcur = xnext;
        if (t < 128 && step + 1 < HWN)
            xnext = (float)xb[(size_t)(step + 1) * RH + t];

        // ---- partial y for 4 rows over this thread's 16 h-pairs
        uint4 q0 = hq[sl*4+0], q1 = hq[sl*4+1], q2 = hq[sl*4+2], q3 = hq[sl*4+3];
        f16x2 H0  = __builtin_bit_cast(f16x2, q0.x), H1  = __builtin_bit_cast(f16x2, q0.y);
        f16x2 H2  = __builtin_bit_cast(f16x2, q0.z), H3  = __builtin_bit_cast(f16x2, q0.w);
        f16x2 H4  = __builtin_bit_cast(f16x2, q1.x), H5  = __builtin_bit_cast(f16x2, q1.y);
        f16x2 H6  = __builtin_bit_cast(f16x2, q1.z), H7  = __builtin_bit_cast(f16x2, q1.w);
        f16x2 H8  = __builtin_bit_cast(f16x2, q2.x), H9  = __builtin_bit_cast(f16x2, q2.y);
        f16x2 H10 = __builtin_bit_cast(f16x2, q2.z), H11 = __builtin_bit_cast(f16x2, q2.w);
        f16x2 H12 = __builtin_bit_cast(f16x2, q3.x), H13 = __builtin_bit_cast(f16x2, q3.y);
        f16x2 H14 = __builtin_bit_cast(f16x2, q3.z), H15 = __builtin_bit_cast(f16x2, q3.w);
        float a0 = 0.f, a1 = 0.f, a2 = 0.f, a3 = 0.f;
        ROW16(a0, W0,  W1,  W2,  W3);
        ROW16(a1, W4,  W5,  W6,  W7);
        ROW16(a2, W8,  W9,  W10, W11);
        ROW16(a3, W12, W13, W14, W15);
        *(f32x4*)&part[sl][4 * jg] = (f32x4){a0, a1, a2, a3};
        __syncthreads();

        const u32 tag = (u32)(step + 1);
        const size_t pbase = (size_t)(tag & 1) * 8192;

        // ---- waves 4-6: poll for the 3 partner slices (start immediately)
        if (t >= 256 && t < 448) {
            int pi = (t - 256) >> 6;
            int widx = t & 63;
            int p = pi + (pi >= s ? 1 : 0);
            u64* addr = &cb[pbase + p * 64 + widx];
            u64 v  = __hip_atomic_load(addr, __ATOMIC_RELAXED, __HIP_MEMORY_SCOPE_AGENT);
            u64 v2 = __hip_atomic_load(addr, __ATOMIC_RELAXED, __HIP_MEMORY_SCOPE_AGENT);
            int guard = 0;
            while ((u32)(v >> 32) != tag && ++guard < (1 << 17)) {
                v = v2;
                v2 = __hip_atomic_load(addr, __ATOMIC_RELAXED, __HIP_MEMORY_SCOPE_AGENT);
            }
            ((u32*)hbuf)[p * 64 + widx] = (u32)v;
        }
        // ---- waves 0-1: finalize own 128 rows, publish ASAP
        if (t < 128) {
            float y = xcur;
            #pragma unroll
            for (int k = 0; k < 16; k++) y += part[k][t];
            float h = tanhf(y);
            f16 hf = (f16)h;
            u32 hu = (u32)__builtin_bit_cast(unsigned short, hf);
            u32 other = (u32)__shfl_down((int)hu, 1, 64);
            if ((t & 1) == 0) {
                u64 v = ((u64)tag << 32) | (u64)(hu | (other << 16));
                __hip_atomic_store(&cb[pbase + s * 64 + (t >> 1)], v,
                                   __ATOMIC_RELAXED, __HIP_MEMORY_SCOPE_AGENT);
            }
            hbuf[s * 128 + t] = hf;                 // own slice into local h
            xb[(size_t)step * RH + t] = hf;         // hs output (in place)
        }
        __syncthreads();
    }
}

// ------------------------------------------------------------------ launch
extern "C" void kernel_launch(void* const* d_in, const int* in_sizes, int n_in,
                              void* d_out, int out_size, void* d_ws, size_t ws_size,
                              hipStream_t stream) {
    const float* x     = (const float*)d_in[0];
    const float* gamma = (const float*)d_in[1];
    const float* beta  = (const float*)d_in[2];
    const float* w_in  = (const float*)d_in[3];
    const float* b_in  = (const float*)d_in[4];
    const float* w_ih  = (const float*)d_in[5];
    const float* b_ih  = (const float*)d_in[6];
    const float* w_hh  = (const float*)d_in[7];
    const float* b_hh  = (const float*)d_in[8];
    const float* w_out = (const float*)d_in[9];
    const float* b_out = (const float*)d_in[10];

    char* ws = (char*)d_ws;
    float* scale   = (float*)(ws + 0);         //   512 B
    float* shift   = (float*)(ws + 512);       //   512 B
    float* bihh    = (float*)(ws + 1024);      //  2 KB
    f16*   w_in_h  = (f16*)(ws + 4096);        // 64 KB
    f16*   w_ih_h  = (f16*)(ws + 69632);       // 256 KB
    f16*   w_out_h = (f16*)(ws + 331776);      // 128 KB
    u32*   wr      = (u32*)(ws + 462848);      // 512 KB packed W_hh
    u64*   comm    = (u64*)(ws + 987136);      // 128 KB h-exchange
    f16*   xh      = (f16*)(ws + 1179648);     // 32 MB xgate, overwritten by hs
    f16*   A1      = (f16*)(ws + 34734080);    //  8 MB
    f16*   inp     = (f16*)(ws + 43122688);    // 16 MB (ends 59899904)

    bn_stats_kernel<<<128, 256, 0, stream>>>(x, gamma, beta, scale, shift);
    prep_w_kernel<<<1474, 256, 0, stream>>>(w_in, w_ih, w_out, w_hh, b_ih, b_hh,
                                            w_in_h, w_ih_h, w_out_h, wr, bihh, comm);
    prep_x_kernel<<<dim3(32, 4, 32), dim3(32, 8), 0, stream>>>(x, scale, shift, A1);
    gemm_kernel<0><<<dim3(128, 4), 256, 0, stream>>>(A1, w_in_h, b_in, (void*)inp, RIN, CC);
    gemm_kernel<1><<<dim3(128, 8), 256, 0, stream>>>(inp, w_ih_h, bihh, (void*)xh, RH, RIN);
    rnn_kernel<<<128, 512, 0, stream>>>(wr, xh, comm);
    gemm_kernel<2><<<dim3(128, 2), 256, 0, stream>>>(xh, w_out_h, b_out, d_out, OCN, RH);
}